// Round 2
// baseline (480.012 us; speedup 1.0000x reference)
//
#include <hip/hip_runtime.h>

#define Nn 256
#define Cc 128
#define Pp 275
#define Dd 128

typedef unsigned int u32;
typedef unsigned short u16;

__device__ __forceinline__ float bf2f(u16 h) {
    return __uint_as_float(((u32)h) << 16);
}
__device__ __forceinline__ u16 f2bf(float f) {
    u32 u = __float_as_uint(f);
    return (u16)((u + 0x7fffu + ((u >> 16) & 1u)) >> 16);
}

// online logsumexp update
#define UPD(mx, s, v)                                        \
    do {                                                     \
        if ((v) <= (mx)) {                                   \
            s += __expf((v) - (mx));                         \
        } else {                                             \
            s = s * __expf((mx) - (v)) + 1.f;                \
            mx = (v);                                        \
        }                                                    \
    } while (0)

// ---------------- K1: bias_t / bias_p (N x D) ----------------
__global__ __launch_bounds__(256) void bias_kernel(
    const float* __restrict__ m_t, const float* __restrict__ m_p,
    const float* __restrict__ c_t, const float* __restrict__ c_p,
    const float* __restrict__ W, const float* __restrict__ b,
    float* __restrict__ bias_t, float* __restrict__ bias_p)
{
    int idx = blockIdx.x * 256 + threadIdx.x;   // N*D = 32768
    int n = idx >> 7, d = idx & 127;
    float at = 0.f, ap = 0.f;
#pragma unroll 8
    for (int k = 0; k < 64; ++k) {
        float wm = W[(128 + k) * 128 + d];
        float wc = W[(192 + k) * 128 + d];
        at = fmaf(m_t[n * 64 + k], wm, at);
        at = fmaf(c_t[n * 64 + k], wc, at);
        ap = fmaf(m_p[n * 64 + k], wm, ap);
        ap = fmaf(c_p[n * 64 + k], wc, ap);
    }
    float bb = b[d];
    bias_t[idx] = at + bb;
    bias_p[idx] = ap + bb;
}

// ---------------- K2: pred/pos = loc @ Wl + bias (bf16 out) ----------------
// grid: (pchunk=5, n=256); block handles 64 p values for one n.
__global__ __launch_bounds__(256) void join_kernel(
    const float* __restrict__ x_t, const float* __restrict__ x_p,
    const float* __restrict__ W,
    const float* __restrict__ bias_t, const float* __restrict__ bias_p,
    u16* __restrict__ pred, u16* __restrict__ pos)
{
    __shared__ float xbuf[128 * 64];   // [c][p_local]  32 KB
    __shared__ u16 wl[128 * 128];      // bf16 Wl       32 KB
    const int tid = threadIdx.x;
    const int pc = blockIdx.x;
    const int n = blockIdx.y;
    const int p0 = pc * 64;
    const int pcnt = (Pp - p0 < 64) ? (Pp - p0) : 64;

#pragma unroll 4
    for (int i = 0; i < 64; ++i) {
        int idx = tid + 256 * i;       // 16384 elements of Wl
        wl[idx] = f2bf(W[idx]);
    }

    const int pl = tid & 63;
    const int c0 = tid >> 6;
    const int d  = tid & 127;
    const int ph = tid >> 7;

    for (int pass = 0; pass < 2; ++pass) {
        const float* xg = (pass == 0 ? x_t : x_p) + (size_t)n * (Cc * Pp);
        const float* bias = (pass == 0 ? bias_t : bias_p) + n * Dd;
        u16* outp = (pass == 0 ? pred : pos);
        __syncthreads();
#pragma unroll 4
        for (int i = 0; i < 32; ++i) {
            int c = c0 + 4 * i;
            float v = (pl < pcnt) ? xg[c * Pp + p0 + pl] : 0.f;
            xbuf[c * 64 + pl] = v;
        }
        __syncthreads();
        float bv = bias[d];
        for (int i = 0; i < 8; ++i) {
            int pb = ph * 32 + i * 4;
            float a0 = 0.f, a1 = 0.f, a2 = 0.f, a3 = 0.f;
#pragma unroll 8
            for (int c = 0; c < 128; ++c) {
                float w = bf2f(wl[c * 128 + d]);
                float4 x4 = *reinterpret_cast<const float4*>(&xbuf[c * 64 + pb]);
                a0 = fmaf(x4.x, w, a0);
                a1 = fmaf(x4.y, w, a1);
                a2 = fmaf(x4.z, w, a2);
                a3 = fmaf(x4.w, w, a3);
            }
            int pg = p0 + pb;
            size_t base = ((size_t)pg * Nn + n) * Dd + d;
            const size_t stride = (size_t)Nn * Dd;
            if (pb + 0 < pcnt) outp[base]              = f2bf(a0 + bv);
            if (pb + 1 < pcnt) outp[base + stride]     = f2bf(a1 + bv);
            if (pb + 2 < pcnt) outp[base + 2 * stride] = f2bf(a2 + bv);
            if (pb + 3 < pcnt) outp[base + 3 * stride] = f2bf(a3 + bv);
        }
    }
}

// ---------------- K3: logits + online LSE - diag ----------------
// grid: (ntile=2, p=275); block = 256 threads; quad (4 lanes) owns 2 rows.
__global__ __launch_bounds__(256) void logits_kernel(
    const float* __restrict__ f,
    const u16* __restrict__ pred, const u16* __restrict__ pos,
    float* __restrict__ partial)
{
    __shared__ u16 pos_lds[Nn * Dd];   // 64 KB, pos[p] tile
    const int tid = threadIdx.x;
    const int p = blockIdx.y;
    const int n0 = blockIdx.x * 128;

    {
        // 256x128 u16 tile = 65536 B = 4096 uint4 -> 16 iterations of 256 thr
        const uint4* src = reinterpret_cast<const uint4*>(pos + (size_t)p * (Nn * Dd));
        uint4* dst = reinterpret_cast<uint4*>(pos_lds);
#pragma unroll
        for (int i = 0; i < 16; ++i) dst[tid + 256 * i] = src[tid + 256 * i];
    }

    const int q = tid >> 2;
    const int l = tid & 3;
    const int na = n0 + q;
    const int nb = n0 + 64 + q;
    const int ds = l * 32;

    float fa[32], fb[32], pa[32], pb[32];
#pragma unroll
    for (int j = 0; j < 32; j += 4) {
        float4 t0 = *reinterpret_cast<const float4*>(&f[na * Dd + ds + j]);
        fa[j] = t0.x; fa[j + 1] = t0.y; fa[j + 2] = t0.z; fa[j + 3] = t0.w;
        float4 t1 = *reinterpret_cast<const float4*>(&f[nb * Dd + ds + j]);
        fb[j] = t1.x; fb[j + 1] = t1.y; fb[j + 2] = t1.z; fb[j + 3] = t1.w;
    }
    {
        const uint4* prA = reinterpret_cast<const uint4*>(pred + ((size_t)p * Nn + na) * Dd + ds);
        const uint4* prB = reinterpret_cast<const uint4*>(pred + ((size_t)p * Nn + nb) * Dd + ds);
#pragma unroll
        for (int jj = 0; jj < 4; ++jj) {
            uint4 ua = prA[jj];
            uint4 ub = prB[jj];
            u32 wa[4] = {ua.x, ua.y, ua.z, ua.w};
            u32 wb[4] = {ub.x, ub.y, ub.z, ub.w};
#pragma unroll
            for (int t = 0; t < 4; ++t) {
                int j = jj * 8 + t * 2;
                pa[j]     = __uint_as_float(wa[t] << 16);
                pa[j + 1] = __uint_as_float(wa[t] & 0xffff0000u);
                pb[j]     = __uint_as_float(wb[t] << 16);
                pb[j + 1] = __uint_as_float(wb[t] & 0xffff0000u);
            }
        }
    }

    __syncthreads();

    float mx1a = -1e30f, s1a = 0.f, mx2a = -1e30f, s2a = 0.f;
    float mx1b = -1e30f, s1b = 0.f, mx2b = -1e30f, s2b = 0.f;
    float d1a = 0.f, d2a = 0.f, d1b = 0.f, d2b = 0.f;

    for (int m = 0; m < Nn; ++m) {
        const uint4* pr4 = reinterpret_cast<const uint4*>(&pos_lds[m * Dd + ds]);
        float v1a = 0.f, v2a = 0.f, v1b = 0.f, v2b = 0.f;
#pragma unroll
        for (int jj = 0; jj < 4; ++jj) {
            uint4 u = pr4[jj];
            u32 w_[4] = {u.x, u.y, u.z, u.w};
#pragma unroll
            for (int t = 0; t < 4; ++t) {
                int j = jj * 8 + t * 2;
                float plo = __uint_as_float(w_[t] << 16);
                float phi = __uint_as_float(w_[t] & 0xffff0000u);
                v1a = fmaf(fa[j], plo, v1a); v1a = fmaf(fa[j + 1], phi, v1a);
                v2a = fmaf(pa[j], plo, v2a); v2a = fmaf(pa[j + 1], phi, v2a);
                v1b = fmaf(fb[j], plo, v1b); v1b = fmaf(fb[j + 1], phi, v1b);
                v2b = fmaf(pb[j], plo, v2b); v2b = fmaf(pb[j + 1], phi, v2b);
            }
        }
        v1a += __shfl_xor(v1a, 1); v1a += __shfl_xor(v1a, 2);
        v2a += __shfl_xor(v2a, 1); v2a += __shfl_xor(v2a, 2);
        v1b += __shfl_xor(v1b, 1); v1b += __shfl_xor(v1b, 2);
        v2b += __shfl_xor(v2b, 1); v2b += __shfl_xor(v2b, 2);
        if (m == na) { d1a = v1a; d2a = v2a; }
        if (m == nb) { d1b = v1b; d2b = v2b; }
        UPD(mx1a, s1a, v1a);
        UPD(mx2a, s2a, v2a);
        UPD(mx1b, s1b, v1b);
        UPD(mx2b, s2b, v2b);
    }

    float r = (mx1a + __logf(s1a) - d1a) + (mx2a + __logf(s2a) - d2a)
            + (mx1b + __logf(s1b) - d1b) + (mx2b + __logf(s2b) - d2b);
    float val = (l == 0) ? r : 0.f;

    __syncthreads();
    float* red = reinterpret_cast<float*>(pos_lds);
    red[tid] = val;
    __syncthreads();
    for (int k = 128; k > 0; k >>= 1) {
        if (tid < k) red[tid] += red[tid + k];
        __syncthreads();
    }
    if (tid == 0) partial[blockIdx.y * 2 + blockIdx.x] = red[0];
}

// ---------------- K4: deterministic final reduce ----------------
__global__ __launch_bounds__(256) void reduce_kernel(
    const float* __restrict__ partial, float* __restrict__ out)
{
    __shared__ float red[256];
    float s = 0.f;
    for (int i = threadIdx.x; i < 2 * Pp; i += 256) s += partial[i];
    red[threadIdx.x] = s;
    __syncthreads();
    for (int k = 128; k > 0; k >>= 1) {
        if (threadIdx.x < k) red[threadIdx.x] += red[threadIdx.x + k];
        __syncthreads();
    }
    if (threadIdx.x == 0) out[0] = red[0] * (1.0f / (Pp * (float)Nn));
}

extern "C" void kernel_launch(void* const* d_in, const int* in_sizes, int n_in,
                              void* d_out, int out_size, void* d_ws, size_t ws_size,
                              hipStream_t stream)
{
    const float* f   = (const float*)d_in[0];
    const float* x_t = (const float*)d_in[1];
    const float* x_p = (const float*)d_in[2];
    const float* m_t = (const float*)d_in[3];
    const float* m_p = (const float*)d_in[4];
    const float* c_t = (const float*)d_in[5];
    const float* c_p = (const float*)d_in[6];
    const float* W   = (const float*)d_in[7];
    const float* b   = (const float*)d_in[8];

    char* ws = (char*)d_ws;
    float* bias_t = (float*)ws;
    float* bias_p = bias_t + Nn * Dd;
    u16* pred = (u16*)(ws + 2 * (size_t)Nn * Dd * sizeof(float));
    u16* pos  = pred + (size_t)Pp * Nn * Dd;
    float* partial = (float*)(ws + 2 * (size_t)Nn * Dd * sizeof(float)
                                 + 2 * (size_t)Pp * Nn * Dd * sizeof(u16));

    bias_kernel<<<dim3(Nn * Dd / 256), 256, 0, stream>>>(m_t, m_p, c_t, c_p, W, b, bias_t, bias_p);
    join_kernel<<<dim3(5, Nn), 256, 0, stream>>>(x_t, x_p, W, bias_t, bias_p, pred, pos);
    logits_kernel<<<dim3(2, Pp), 256, 0, stream>>>(f, pred, pos, partial);
    reduce_kernel<<<1, 256, 0, stream>>>(partial, (float*)d_out);
}

// Round 3
// 237.833 us; speedup vs baseline: 2.0183x; 2.0183x over previous
//
#include <hip/hip_runtime.h>

#define Nn 256
#define Cc 128
#define Pp 275
#define Dd 128

typedef unsigned int u32;
typedef unsigned short u16;
typedef float f32x4 __attribute__((ext_vector_type(4)));
typedef short bf16x8 __attribute__((ext_vector_type(8)));

__device__ __forceinline__ float bf2f(u16 h) {
    return __uint_as_float(((u32)h) << 16);
}
__device__ __forceinline__ u16 f2bf(float f) {
    u32 u = __float_as_uint(f);
    return (u16)((u + 0x7fffu + ((u >> 16) & 1u)) >> 16);
}

// ---------------- K1: bias_t / bias_p (N x D) + f -> bf16 ----------------
__global__ __launch_bounds__(256) void bias_kernel(
    const float* __restrict__ m_t, const float* __restrict__ m_p,
    const float* __restrict__ c_t, const float* __restrict__ c_p,
    const float* __restrict__ W, const float* __restrict__ b,
    const float* __restrict__ f,
    float* __restrict__ bias_t, float* __restrict__ bias_p,
    u16* __restrict__ f_bf)
{
    int idx = blockIdx.x * 256 + threadIdx.x;   // N*D = 32768
    int n = idx >> 7, d = idx & 127;
    float at = 0.f, ap = 0.f;
#pragma unroll 8
    for (int k = 0; k < 64; ++k) {
        float wm = W[(128 + k) * 128 + d];
        float wc = W[(192 + k) * 128 + d];
        at = fmaf(m_t[n * 64 + k], wm, at);
        at = fmaf(c_t[n * 64 + k], wc, at);
        ap = fmaf(m_p[n * 64 + k], wm, ap);
        ap = fmaf(c_p[n * 64 + k], wc, ap);
    }
    float bb = b[d];
    bias_t[idx] = at + bb;
    bias_p[idx] = ap + bb;
    f_bf[idx] = f2bf(f[idx]);
}

// ---------------- K2: pred/pos = loc @ Wl + bias (bf16 out) ----------------
// grid: (pchunk=5, n=256); block handles 64 p values for one n.
__global__ __launch_bounds__(256) void join_kernel(
    const float* __restrict__ x_t, const float* __restrict__ x_p,
    const float* __restrict__ W,
    const float* __restrict__ bias_t, const float* __restrict__ bias_p,
    u16* __restrict__ pred, u16* __restrict__ pos)
{
    __shared__ float xbuf[128 * 64];   // [c][p_local]  32 KB
    __shared__ u16 wl[128 * 128];      // bf16 Wl       32 KB
    const int tid = threadIdx.x;
    const int pc = blockIdx.x;
    const int n = blockIdx.y;
    const int p0 = pc * 64;
    const int pcnt = (Pp - p0 < 64) ? (Pp - p0) : 64;

#pragma unroll 4
    for (int i = 0; i < 64; ++i) {
        int idx = tid + 256 * i;       // 16384 elements of Wl
        wl[idx] = f2bf(W[idx]);
    }

    const int pl = tid & 63;
    const int c0 = tid >> 6;
    const int d  = tid & 127;
    const int ph = tid >> 7;

    for (int pass = 0; pass < 2; ++pass) {
        const float* xg = (pass == 0 ? x_t : x_p) + (size_t)n * (Cc * Pp);
        const float* bias = (pass == 0 ? bias_t : bias_p) + n * Dd;
        u16* outp = (pass == 0 ? pred : pos);
        __syncthreads();
#pragma unroll 4
        for (int i = 0; i < 32; ++i) {
            int c = c0 + 4 * i;
            float v = (pl < pcnt) ? xg[c * Pp + p0 + pl] : 0.f;
            xbuf[c * 64 + pl] = v;
        }
        __syncthreads();
        float bv = bias[d];
        for (int i = 0; i < 8; ++i) {
            int pb = ph * 32 + i * 4;
            float a0 = 0.f, a1 = 0.f, a2 = 0.f, a3 = 0.f;
#pragma unroll 8
            for (int c = 0; c < 128; ++c) {
                float w = bf2f(wl[c * 128 + d]);
                float4 x4 = *reinterpret_cast<const float4*>(&xbuf[c * 64 + pb]);
                a0 = fmaf(x4.x, w, a0);
                a1 = fmaf(x4.y, w, a1);
                a2 = fmaf(x4.z, w, a2);
                a3 = fmaf(x4.w, w, a3);
            }
            int pg = p0 + pb;
            size_t base = ((size_t)pg * Nn + n) * Dd + d;
            const size_t stride = (size_t)Nn * Dd;
            if (pb + 0 < pcnt) outp[base]              = f2bf(a0 + bv);
            if (pb + 1 < pcnt) outp[base + stride]     = f2bf(a1 + bv);
            if (pb + 2 < pcnt) outp[base + 2 * stride] = f2bf(a2 + bv);
            if (pb + 3 < pcnt) outp[base + 3 * stride] = f2bf(a3 + bv);
        }
    }
}

// ---------------- K3: MFMA logits + fixed-shift LSE - diag ----------------
// grid: 275 blocks (one per p); 512 threads = 8 waves.
// Wave w: matrix sel=w&1 (0: S1=f.pos^T, 1: S2=pred.pos^T), rows r0=(w>>1)*64.
__global__ __launch_bounds__(512) void logits_mfma_kernel(
    const u16* __restrict__ f_bf,
    const u16* __restrict__ pred, const u16* __restrict__ pos,
    float* __restrict__ partial)
{
    __shared__ u16 lds[Nn * Dd];   // 64 KB swizzled pos[p] tile
    const int tid = threadIdx.x;
    const int p = blockIdx.x;
    const int w = tid >> 6;
    const int l = tid & 63;
    const int sel = w & 1;
    const int r0 = (w >> 1) << 6;

    // stage pos[p] into LDS, XOR-swizzled: byte ^= ((row&7)<<4)
    {
        const uint4* src = reinterpret_cast<const uint4*>(pos + (size_t)p * (Nn * Dd));
#pragma unroll
        for (int it = 0; it < 8; ++it) {
            int j = tid + 512 * it;            // 4096 uint4 total
            int row = j >> 4;                  // 16 uint4 per 256B row
            int colb = (j & 15) << 4;
            uint4 v = src[j];
            *reinterpret_cast<uint4*>((char*)lds + row * 256 + (colb ^ ((row & 7) << 4))) = v;
        }
    }

    // preload A fragments from global (f_bf or pred[p]), rows r0..r0+63
    const u16* Abase = sel ? (pred + (size_t)p * (Nn * Dd)) : f_bf;
    bf16x8 A[4][4];
    {
        const int arow = l & 15;
        const int acol = (l >> 4) << 4;        // byte offset within 64B k-block
#pragma unroll
        for (int rt = 0; rt < 4; ++rt)
#pragma unroll
            for (int kk = 0; kk < 4; ++kk) {
                const char* ap = (const char*)Abase
                               + (size_t)(r0 + rt * 16 + arow) * 256 + kk * 64 + acol;
                A[rt][kk] = *reinterpret_cast<const bf16x8*>(ap);
            }
    }

    __syncthreads();

    const float L2E = 1.4426950408889634f;
    float s_[4][4];
    float dg[4][4];
#pragma unroll
    for (int rt = 0; rt < 4; ++rt)
#pragma unroll
        for (int r = 0; r < 4; ++r) { s_[rt][r] = 0.f; dg[rt][r] = 0.f; }

    const int mcol = l & 15;                   // B col within tile
    const int bcol = (l >> 4) << 4;

    for (int ct = 0; ct < 16; ++ct) {
        bf16x8 B[4];
        const int mrow = ct * 16 + mcol;
#pragma unroll
        for (int kk = 0; kk < 4; ++kk) {
            int cb = kk * 64 + bcol;
            B[kk] = *reinterpret_cast<const bf16x8*>(
                (const char*)lds + mrow * 256 + (cb ^ ((mrow & 7) << 4)));
        }
#pragma unroll
        for (int rt = 0; rt < 4; ++rt) {
            f32x4 acc = {0.f, 0.f, 0.f, 0.f};
#pragma unroll
            for (int kk = 0; kk < 4; ++kk)
                acc = __builtin_amdgcn_mfma_f32_16x16x32_bf16(A[rt][kk], B[kk], acc, 0, 0, 0);
            const bool isdg_ct = (ct == ((r0 >> 4) + rt));
#pragma unroll
            for (int r = 0; r < 4; ++r) {
                float v = acc[r];
                // s += 2^(v*log2e - 64)
                s_[rt][r] += __builtin_amdgcn_exp2f(fmaf(v, L2E, -64.f));
                if (isdg_ct && ((l & 15) == (((l >> 4) << 2) + r))) dg[rt][r] = v;
            }
        }
    }

    // merge s across the 16 lanes holding the same row; diag lane contributes lse-diag
    float local = 0.f;
#pragma unroll
    for (int rt = 0; rt < 4; ++rt)
#pragma unroll
        for (int r = 0; r < 4; ++r) {
            float s = s_[rt][r];
            s += __shfl_xor(s, 1);
            s += __shfl_xor(s, 2);
            s += __shfl_xor(s, 4);
            s += __shfl_xor(s, 8);
            if ((l & 15) == (((l >> 4) << 2) + r))
                local += 0.6931471805599453f * (64.f + __log2f(s)) - dg[rt][r];
        }

    // block reduce 512 -> 1
    __syncthreads();
    float* red = reinterpret_cast<float*>(lds);
    red[tid] = local;
    __syncthreads();
    for (int k = 256; k > 0; k >>= 1) {
        if (tid < k) red[tid] += red[tid + k];
        __syncthreads();
    }
    if (tid == 0) partial[p] = red[0];
}

// ---------------- K4: deterministic final reduce ----------------
__global__ __launch_bounds__(256) void reduce_kernel(
    const float* __restrict__ partial, float* __restrict__ out)
{
    __shared__ float red[256];
    float s = 0.f;
    for (int i = threadIdx.x; i < Pp; i += 256) s += partial[i];
    red[threadIdx.x] = s;
    __syncthreads();
    for (int k = 128; k > 0; k >>= 1) {
        if (threadIdx.x < k) red[threadIdx.x] += red[threadIdx.x + k];
        __syncthreads();
    }
    if (threadIdx.x == 0) out[0] = red[0] * (1.0f / (Pp * (float)Nn));
}

extern "C" void kernel_launch(void* const* d_in, const int* in_sizes, int n_in,
                              void* d_out, int out_size, void* d_ws, size_t ws_size,
                              hipStream_t stream)
{
    const float* f   = (const float*)d_in[0];
    const float* x_t = (const float*)d_in[1];
    const float* x_p = (const float*)d_in[2];
    const float* m_t = (const float*)d_in[3];
    const float* m_p = (const float*)d_in[4];
    const float* c_t = (const float*)d_in[5];
    const float* c_p = (const float*)d_in[6];
    const float* W   = (const float*)d_in[7];
    const float* b   = (const float*)d_in[8];

    char* ws = (char*)d_ws;
    float* bias_t = (float*)ws;
    float* bias_p = bias_t + Nn * Dd;
    u16* f_bf = (u16*)(ws + 2 * (size_t)Nn * Dd * sizeof(float));
    u16* pred = f_bf + (size_t)Nn * Dd;
    u16* pos  = pred + (size_t)Pp * Nn * Dd;
    float* partial = (float*)((char*)(pos + (size_t)Pp * Nn * Dd));

    bias_kernel<<<dim3(Nn * Dd / 256), 256, 0, stream>>>(m_t, m_p, c_t, c_p, W, b, f,
                                                         bias_t, bias_p, f_bf);
    join_kernel<<<dim3(5, Nn), 256, 0, stream>>>(x_t, x_p, W, bias_t, bias_p, pred, pos);
    logits_mfma_kernel<<<dim3(Pp), 512, 0, stream>>>(f_bf, pred, pos, partial);
    reduce_kernel<<<1, 256, 0, stream>>>(partial, (float*)d_out);
}

// Round 4
// 96.824 us; speedup vs baseline: 4.9576x; 2.4563x over previous
//
#include <hip/hip_runtime.h>

#define Nn 256
#define Cc 128
#define Pp 275
#define Dd 128

typedef unsigned int u32;
typedef unsigned short u16;
typedef float f32x4 __attribute__((ext_vector_type(4)));
typedef short bf16x8 __attribute__((ext_vector_type(8)));

__device__ __forceinline__ float bf2f(u16 h) {
    return __uint_as_float(((u32)h) << 16);
}
__device__ __forceinline__ u16 f2bf(float f) {
    u32 u = __float_as_uint(f);
    return (u16)((u + 0x7fffu + ((u >> 16) & 1u)) >> 16);
}

// ---------------- K1: bias_t / bias_p (N x D) + f->bf16 + Wl^T bf16 ----------------
__global__ __launch_bounds__(256) void bias_kernel(
    const float* __restrict__ m_t, const float* __restrict__ m_p,
    const float* __restrict__ c_t, const float* __restrict__ c_p,
    const float* __restrict__ W, const float* __restrict__ b,
    const float* __restrict__ f,
    float* __restrict__ bias_t, float* __restrict__ bias_p,
    u16* __restrict__ f_bf, u16* __restrict__ WlT)
{
    int idx = blockIdx.x * 256 + threadIdx.x;   // N*D = 32768
    int n = idx >> 7, d = idx & 127;
    float at = 0.f, ap = 0.f;
#pragma unroll 8
    for (int k = 0; k < 64; ++k) {
        float wm = W[(128 + k) * 128 + d];
        float wc = W[(192 + k) * 128 + d];
        at = fmaf(m_t[n * 64 + k], wm, at);
        at = fmaf(c_t[n * 64 + k], wc, at);
        ap = fmaf(m_p[n * 64 + k], wm, ap);
        ap = fmaf(c_p[n * 64 + k], wc, ap);
    }
    float bb = b[d];
    bias_t[idx] = at + bb;
    bias_p[idx] = ap + bb;
    f_bf[idx] = f2bf(f[idx]);
    if (idx < 16384) {                 // WlT[d][c] = Wl[c][d]
        int dd = idx >> 7, cc = idx & 127;
        WlT[idx] = f2bf(W[cc * 128 + dd]);
    }
}

// ---------------- K2a: transpose x[n][c][p] fp32 -> xT[n][p][c] bf16 ----------------
// grid (5, 256), 256 threads; LDS tile [128 c][64 p] padded.
__global__ __launch_bounds__(256) void transpose_kernel(
    const float* __restrict__ x_t, const float* __restrict__ x_p,
    u16* __restrict__ xT_t, u16* __restrict__ xT_p)
{
    __shared__ float lds[128][65];
    const int tid = threadIdx.x;
    const int pc = blockIdx.x;        // 0..4
    const int n  = blockIdx.y;
    const int p0 = pc * 64;
    const int pl = tid & 63;
    const int cb = tid >> 6;          // 0..3 (also wave id)

    for (int pass = 0; pass < 2; ++pass) {
        const float* xg = (pass ? x_p : x_t) + (size_t)n * (Cc * Pp);
        u16* xT = (pass ? xT_p : xT_t) + (size_t)n * (Pp * Dd);
        __syncthreads();
#pragma unroll
        for (int i = 0; i < 32; ++i) {
            int c = cb * 32 + i;
            float v = (p0 + pl < Pp) ? xg[c * Pp + p0 + pl] : 0.f;
            lds[c][pl] = v;
        }
        __syncthreads();
#pragma unroll
        for (int jj = 0; jj < 16; ++jj) {
            int p = cb * 16 + jj;     // p-local 0..63
            if (p0 + p < Pp) {
                float f0 = lds[2 * pl][p];
                float f1 = lds[2 * pl + 1][p];
                u32 pk = (u32)f2bf(f0) | ((u32)f2bf(f1) << 16);
                *reinterpret_cast<u32*>(xT + (size_t)(p0 + p) * Dd + 2 * pl) = pk;
            }
        }
    }
}

// ---------------- K2b: pred/pos = xT @ Wl + bias via MFMA ----------------
// grid 256 (one n per block), 512 threads = 8 waves.
__global__ __launch_bounds__(512) void join_mfma_kernel(
    const u16* __restrict__ xT_t, const u16* __restrict__ xT_p,
    const u16* __restrict__ WlT,
    const float* __restrict__ bias_t, const float* __restrict__ bias_p,
    u16* __restrict__ pred, u16* __restrict__ pos)
{
    __shared__ u16 lds[128 * 128];   // 32 KB swizzled WlT
    const int tid = threadIdx.x;
    const int n = blockIdx.x;
    const int w = tid >> 6;
    const int l = tid & 63;

    {   // stage WlT swizzled: 2048 uint4
        const uint4* src = reinterpret_cast<const uint4*>(WlT);
#pragma unroll
        for (int it = 0; it < 4; ++it) {
            int j = tid + 512 * it;
            int row = j >> 4;
            int colb = (j & 15) << 4;
            uint4 v = src[j];
            *reinterpret_cast<uint4*>((char*)lds + row * 256 + (colb ^ ((row & 7) << 4))) = v;
        }
    }

    float bvT[8], bvP[8];
#pragma unroll
    for (int dt = 0; dt < 8; ++dt) {
        int d = dt * 16 + (l & 15);
        bvT[dt] = bias_t[n * 128 + d];
        bvP[dt] = bias_p[n * 128 + d];
    }

    __syncthreads();

    const u16* xt = xT_t + (size_t)n * (Pp * Dd);
    const u16* xp = xT_p + (size_t)n * (Pp * Dd);

    for (int t = w; t < 18; t += 8) {          // 18 p-tiles of 16
        const int p0 = t * 16;
        bf16x8 At[4], Ap[4];
        {
            int p = p0 + (l & 15);
            if (p > Pp - 1) p = Pp - 1;        // clamp tail (results masked at store)
            const char* rowt = (const char*)xt + (size_t)p * 256 + ((l >> 4) << 4);
            const char* rowp = (const char*)xp + (size_t)p * 256 + ((l >> 4) << 4);
#pragma unroll
            for (int kk = 0; kk < 4; ++kk) {
                At[kk] = *reinterpret_cast<const bf16x8*>(rowt + kk * 64);
                Ap[kk] = *reinterpret_cast<const bf16x8*>(rowp + kk * 64);
            }
        }
#pragma unroll
        for (int dt = 0; dt < 8; ++dt) {
            bf16x8 B[4];
            const int row = dt * 16 + (l & 15);
#pragma unroll
            for (int kk = 0; kk < 4; ++kk) {
                int cbyte = kk * 64 + ((l >> 4) << 4);
                B[kk] = *reinterpret_cast<const bf16x8*>(
                    (const char*)lds + row * 256 + (cbyte ^ ((row & 7) << 4)));
            }
            f32x4 aT = {0.f, 0.f, 0.f, 0.f}, aP = {0.f, 0.f, 0.f, 0.f};
#pragma unroll
            for (int kk = 0; kk < 4; ++kk) {
                aT = __builtin_amdgcn_mfma_f32_16x16x32_bf16(At[kk], B[kk], aT, 0, 0, 0);
                aP = __builtin_amdgcn_mfma_f32_16x16x32_bf16(Ap[kk], B[kk], aP, 0, 0, 0);
            }
            const int d = dt * 16 + (l & 15);
#pragma unroll
            for (int r = 0; r < 4; ++r) {
                int p = p0 + ((l >> 4) << 2) + r;
                if (p < Pp) {
                    size_t o = ((size_t)p * Nn + n) * Dd + d;
                    pred[o] = f2bf(aT[r] + bvT[dt]);
                    pos[o]  = f2bf(aP[r] + bvP[dt]);
                }
            }
        }
    }
}

// ---------------- old fp32 join (fallback if ws too small) ----------------
__global__ __launch_bounds__(256) void join_kernel(
    const float* __restrict__ x_t, const float* __restrict__ x_p,
    const float* __restrict__ W,
    const float* __restrict__ bias_t, const float* __restrict__ bias_p,
    u16* __restrict__ pred, u16* __restrict__ pos)
{
    __shared__ float xbuf[128 * 64];
    __shared__ u16 wl[128 * 128];
    const int tid = threadIdx.x;
    const int pc = blockIdx.x;
    const int n = blockIdx.y;
    const int p0 = pc * 64;
    const int pcnt = (Pp - p0 < 64) ? (Pp - p0) : 64;

#pragma unroll 4
    for (int i = 0; i < 64; ++i) {
        int idx = tid + 256 * i;
        wl[idx] = f2bf(W[idx]);
    }

    const int pl = tid & 63;
    const int c0 = tid >> 6;
    const int d  = tid & 127;
    const int ph = tid >> 7;

    for (int pass = 0; pass < 2; ++pass) {
        const float* xg = (pass == 0 ? x_t : x_p) + (size_t)n * (Cc * Pp);
        const float* bias = (pass == 0 ? bias_t : bias_p) + n * Dd;
        u16* outp = (pass == 0 ? pred : pos);
        __syncthreads();
#pragma unroll 4
        for (int i = 0; i < 32; ++i) {
            int c = c0 + 4 * i;
            float v = (pl < pcnt) ? xg[c * Pp + p0 + pl] : 0.f;
            xbuf[c * 64 + pl] = v;
        }
        __syncthreads();
        float bv = bias[d];
        for (int i = 0; i < 8; ++i) {
            int pb = ph * 32 + i * 4;
            float a0 = 0.f, a1 = 0.f, a2 = 0.f, a3 = 0.f;
#pragma unroll 8
            for (int c = 0; c < 128; ++c) {
                float w = bf2f(wl[c * 128 + d]);
                float4 x4 = *reinterpret_cast<const float4*>(&xbuf[c * 64 + pb]);
                a0 = fmaf(x4.x, w, a0);
                a1 = fmaf(x4.y, w, a1);
                a2 = fmaf(x4.z, w, a2);
                a3 = fmaf(x4.w, w, a3);
            }
            int pg = p0 + pb;
            size_t base = ((size_t)pg * Nn + n) * Dd + d;
            const size_t stride = (size_t)Nn * Dd;
            if (pb + 0 < pcnt) outp[base]              = f2bf(a0 + bv);
            if (pb + 1 < pcnt) outp[base + stride]     = f2bf(a1 + bv);
            if (pb + 2 < pcnt) outp[base + 2 * stride] = f2bf(a2 + bv);
            if (pb + 3 < pcnt) outp[base + 3 * stride] = f2bf(a3 + bv);
        }
    }
}

// ---------------- K3: MFMA logits + fixed-shift LSE - diag ----------------
__global__ __launch_bounds__(512) void logits_mfma_kernel(
    const u16* __restrict__ f_bf,
    const u16* __restrict__ pred, const u16* __restrict__ pos,
    float* __restrict__ partial)
{
    __shared__ u16 lds[Nn * Dd];   // 64 KB swizzled pos[p] tile
    const int tid = threadIdx.x;
    const int p = blockIdx.x;
    const int w = tid >> 6;
    const int l = tid & 63;
    const int sel = w & 1;
    const int r0 = (w >> 1) << 6;

    {
        const uint4* src = reinterpret_cast<const uint4*>(pos + (size_t)p * (Nn * Dd));
#pragma unroll
        for (int it = 0; it < 8; ++it) {
            int j = tid + 512 * it;
            int row = j >> 4;
            int colb = (j & 15) << 4;
            uint4 v = src[j];
            *reinterpret_cast<uint4*>((char*)lds + row * 256 + (colb ^ ((row & 7) << 4))) = v;
        }
    }

    const u16* Abase = sel ? (pred + (size_t)p * (Nn * Dd)) : f_bf;
    bf16x8 A[4][4];
    {
        const int arow = l & 15;
        const int acol = (l >> 4) << 4;
#pragma unroll
        for (int rt = 0; rt < 4; ++rt)
#pragma unroll
            for (int kk = 0; kk < 4; ++kk) {
                const char* ap = (const char*)Abase
                               + (size_t)(r0 + rt * 16 + arow) * 256 + kk * 64 + acol;
                A[rt][kk] = *reinterpret_cast<const bf16x8*>(ap);
            }
    }

    __syncthreads();

    const float L2E = 1.4426950408889634f;
    float s_[4][4];
    float dg[4][4];
#pragma unroll
    for (int rt = 0; rt < 4; ++rt)
#pragma unroll
        for (int r = 0; r < 4; ++r) { s_[rt][r] = 0.f; dg[rt][r] = 0.f; }

    const int mcol = l & 15;
    const int bcol = (l >> 4) << 4;

    for (int ct = 0; ct < 16; ++ct) {
        bf16x8 B[4];
        const int mrow = ct * 16 + mcol;
#pragma unroll
        for (int kk = 0; kk < 4; ++kk) {
            int cb = kk * 64 + bcol;
            B[kk] = *reinterpret_cast<const bf16x8*>(
                (const char*)lds + mrow * 256 + (cb ^ ((mrow & 7) << 4)));
        }
#pragma unroll
        for (int rt = 0; rt < 4; ++rt) {
            f32x4 acc = {0.f, 0.f, 0.f, 0.f};
#pragma unroll
            for (int kk = 0; kk < 4; ++kk)
                acc = __builtin_amdgcn_mfma_f32_16x16x32_bf16(A[rt][kk], B[kk], acc, 0, 0, 0);
            const bool isdg_ct = (ct == ((r0 >> 4) + rt));
#pragma unroll
            for (int r = 0; r < 4; ++r) {
                float v = acc[r];
                s_[rt][r] += __builtin_amdgcn_exp2f(fmaf(v, L2E, -64.f));
                if (isdg_ct && ((l & 15) == (((l >> 4) << 2) + r))) dg[rt][r] = v;
            }
        }
    }

    float local = 0.f;
#pragma unroll
    for (int rt = 0; rt < 4; ++rt)
#pragma unroll
        for (int r = 0; r < 4; ++r) {
            float s = s_[rt][r];
            s += __shfl_xor(s, 1);
            s += __shfl_xor(s, 2);
            s += __shfl_xor(s, 4);
            s += __shfl_xor(s, 8);
            if ((l & 15) == (((l >> 4) << 2) + r))
                local += 0.6931471805599453f * (64.f + __log2f(s)) - dg[rt][r];
        }

    __syncthreads();
    float* red = reinterpret_cast<float*>(lds);
    red[tid] = local;
    __syncthreads();
    for (int k = 256; k > 0; k >>= 1) {
        if (tid < k) red[tid] += red[tid + k];
        __syncthreads();
    }
    if (tid == 0) partial[p] = red[0];
}

// ---------------- K4: deterministic final reduce ----------------
__global__ __launch_bounds__(256) void reduce_kernel(
    const float* __restrict__ partial, float* __restrict__ out)
{
    __shared__ float red[256];
    float s = 0.f;
    for (int i = threadIdx.x; i < Pp; i += 256) s += partial[i];
    red[threadIdx.x] = s;
    __syncthreads();
    for (int k = 128; k > 0; k >>= 1) {
        if (threadIdx.x < k) red[threadIdx.x] += red[threadIdx.x + k];
        __syncthreads();
    }
    if (threadIdx.x == 0) out[0] = red[0] * (1.0f / (Pp * (float)Nn));
}

extern "C" void kernel_launch(void* const* d_in, const int* in_sizes, int n_in,
                              void* d_out, int out_size, void* d_ws, size_t ws_size,
                              hipStream_t stream)
{
    const float* f   = (const float*)d_in[0];
    const float* x_t = (const float*)d_in[1];
    const float* x_p = (const float*)d_in[2];
    const float* m_t = (const float*)d_in[3];
    const float* m_p = (const float*)d_in[4];
    const float* c_t = (const float*)d_in[5];
    const float* c_p = (const float*)d_in[6];
    const float* W   = (const float*)d_in[7];
    const float* b   = (const float*)d_in[8];

    char* ws = (char*)d_ws;
    const size_t SLAB = (size_t)Pp * Nn * Dd;     // 9,011,200 elems

    float* bias_t = (float*)ws;                          // 131072 B
    float* bias_p = bias_t + Nn * Dd;                    // 131072 B
    u16* f_bf = (u16*)(ws + 262144);                     // 65536 B
    u16* WlT  = f_bf + Nn * Dd;                          // 32768 B

    // new-path layout
    u16* xT_t = (u16*)(ws + 360448);
    u16* xT_p = xT_t + SLAB;
    u16* pred_n = xT_p + SLAB;
    u16* pos_n  = pred_n + SLAB;
    float* partial_n = (float*)(pos_n + SLAB);
    size_t need_new = 360448 + 4 * SLAB * sizeof(u16) + (Pp + 4) * sizeof(float);

    // fallback layout (old join)
    u16* pred_o = WlT + 16384;
    u16* pos_o  = pred_o + SLAB;
    float* partial_o = (float*)(pos_o + SLAB);

    bias_kernel<<<dim3(Nn * Dd / 256), 256, 0, stream>>>(m_t, m_p, c_t, c_p, W, b, f,
                                                         bias_t, bias_p, f_bf, WlT);
    if (ws_size >= need_new) {
        transpose_kernel<<<dim3(5, Nn), 256, 0, stream>>>(x_t, x_p, xT_t, xT_p);
        join_mfma_kernel<<<dim3(Nn), 512, 0, stream>>>(xT_t, xT_p, WlT, bias_t, bias_p,
                                                       pred_n, pos_n);
        logits_mfma_kernel<<<dim3(Pp), 512, 0, stream>>>(f_bf, pred_n, pos_n, partial_n);
        reduce_kernel<<<1, 256, 0, stream>>>(partial_n, (float*)d_out);
    } else {
        join_kernel<<<dim3(5, Nn), 256, 0, stream>>>(x_t, x_p, W, bias_t, bias_p, pred_o, pos_o);
        logits_mfma_kernel<<<dim3(Pp), 512, 0, stream>>>(f_bf, pred_o, pos_o, partial_o);
        reduce_kernel<<<1, 256, 0, stream>>>(partial_o, (float*)d_out);
    }
}

// Round 5
// 75.008 us; speedup vs baseline: 6.3995x; 1.2909x over previous
//
#include <hip/hip_runtime.h>

#define Nn 256
#define Cc 128
#define Pp 275
#define Dd 128

typedef unsigned int u32;
typedef unsigned short u16;
typedef float f32x4 __attribute__((ext_vector_type(4)));
typedef short bf16x8 __attribute__((ext_vector_type(8)));

__device__ __forceinline__ float bf2f(u16 h) {
    return __uint_as_float(((u32)h) << 16);
}
__device__ __forceinline__ u16 f2bf(float f) {
    u32 u = __float_as_uint(f);
    return (u16)((u + 0x7fffu + ((u >> 16) & 1u)) >> 16);
}

// ---------------- K1: bias_t / bias_p (N x D) + f->bf16 + Wl^T bf16 ----------------
__global__ __launch_bounds__(256) void bias_kernel(
    const float* __restrict__ m_t, const float* __restrict__ m_p,
    const float* __restrict__ c_t, const float* __restrict__ c_p,
    const float* __restrict__ W, const float* __restrict__ b,
    const float* __restrict__ f,
    float* __restrict__ bias_t, float* __restrict__ bias_p,
    u16* __restrict__ f_bf, u16* __restrict__ WlT)
{
    int idx = blockIdx.x * 256 + threadIdx.x;   // N*D = 32768
    int n = idx >> 7, d = idx & 127;
    float at = 0.f, ap = 0.f;
#pragma unroll 8
    for (int k = 0; k < 64; ++k) {
        float wm = W[(128 + k) * 128 + d];
        float wc = W[(192 + k) * 128 + d];
        at = fmaf(m_t[n * 64 + k], wm, at);
        at = fmaf(c_t[n * 64 + k], wc, at);
        ap = fmaf(m_p[n * 64 + k], wm, ap);
        ap = fmaf(c_p[n * 64 + k], wc, ap);
    }
    float bb = b[d];
    bias_t[idx] = at + bb;
    bias_p[idx] = ap + bb;
    f_bf[idx] = f2bf(f[idx]);
    if (idx < 16384) {                 // WlT[d][c] = Wl[c][d]
        int dd = idx >> 7, cc = idx & 127;
        WlT[idx] = f2bf(W[cc * 128 + dd]);
    }
}

// ---------------- K2: fused join — pred/pos = x^T @ Wl + bias, MFMA, direct x reads ----
// grid (5, 256): 4 waves/block, wave owns p-tile t = blockIdx.x*4 + wave (t<18).
__global__ __launch_bounds__(256) void join_direct_kernel(
    const float* __restrict__ x_t, const float* __restrict__ x_p,
    const u16* __restrict__ WlT,
    const float* __restrict__ bias_t, const float* __restrict__ bias_p,
    u16* __restrict__ pred, u16* __restrict__ pos)
{
    __shared__ u16 lds[128 * 128];   // 32 KB swizzled WlT
    const int tid = threadIdx.x;
    const int n = blockIdx.y;
    const int w = tid >> 6;
    const int l = tid & 63;

    {   // stage WlT swizzled: 2048 uint4 over 256 threads
        const uint4* src = reinterpret_cast<const uint4*>(WlT);
#pragma unroll
        for (int it = 0; it < 8; ++it) {
            int j = tid + 256 * it;
            int row = j >> 4;
            int colb = (j & 15) << 4;
            uint4 v = src[j];
            *reinterpret_cast<uint4*>((char*)lds + row * 256 + (colb ^ ((row & 7) << 4))) = v;
        }
    }

    const int t = blockIdx.x * 4 + w;          // p-tile 0..19 (18 used)
    __syncthreads();
    if (t >= 18) return;

    const int p0 = t * 16;
    int prow = p0 + (l & 15);
    if (prow > Pp - 1) prow = Pp - 1;          // clamp tail reads (stores masked)

    const float* xs_t = x_t + (size_t)n * (Cc * Pp) + prow;
    const float* xs_p = x_p + (size_t)n * (Cc * Pp) + prow;

    // load + convert A fragments for both passes: lane needs c = kk*32+(l>>4)*8+e
    bf16x8 At[4], Ap[4];
#pragma unroll
    for (int kk = 0; kk < 4; ++kk) {
        const int c0 = kk * 32 + ((l >> 4) << 3);
        float vt[8], vp[8];
#pragma unroll
        for (int e = 0; e < 8; ++e) vt[e] = xs_t[(size_t)(c0 + e) * Pp];
#pragma unroll
        for (int e = 0; e < 8; ++e) vp[e] = xs_p[(size_t)(c0 + e) * Pp];
        bf16x8 a, c;
#pragma unroll
        for (int e = 0; e < 8; ++e) { a[e] = (short)f2bf(vt[e]); c[e] = (short)f2bf(vp[e]); }
        At[kk] = a;
        Ap[kk] = c;
    }

    float bvT[8], bvP[8];
#pragma unroll
    for (int dt = 0; dt < 8; ++dt) {
        int d = dt * 16 + (l & 15);
        bvT[dt] = bias_t[n * 128 + d];
        bvP[dt] = bias_p[n * 128 + d];
    }

#pragma unroll
    for (int dt = 0; dt < 8; ++dt) {
        bf16x8 B[4];
        const int row = dt * 16 + (l & 15);
#pragma unroll
        for (int kk = 0; kk < 4; ++kk) {
            int cbyte = kk * 64 + ((l >> 4) << 4);
            B[kk] = *reinterpret_cast<const bf16x8*>(
                (const char*)lds + row * 256 + (cbyte ^ ((row & 7) << 4)));
        }
        f32x4 aT = {0.f, 0.f, 0.f, 0.f}, aP = {0.f, 0.f, 0.f, 0.f};
#pragma unroll
        for (int kk = 0; kk < 4; ++kk) {
            aT = __builtin_amdgcn_mfma_f32_16x16x32_bf16(At[kk], B[kk], aT, 0, 0, 0);
            aP = __builtin_amdgcn_mfma_f32_16x16x32_bf16(Ap[kk], B[kk], aP, 0, 0, 0);
        }
        const int d = dt * 16 + (l & 15);
#pragma unroll
        for (int r = 0; r < 4; ++r) {
            int p = p0 + ((l >> 4) << 2) + r;
            if (p < Pp) {
                size_t o = ((size_t)p * Nn + n) * Dd + d;
                pred[o] = f2bf(aT[r] + bvT[dt]);
                pos[o]  = f2bf(aP[r] + bvP[dt]);
            }
        }
    }
}

// ---------------- K3: MFMA logits + fixed-shift LSE - diag ----------------
// grid (Pp, 2): sel = blockIdx.y (0: S1=f.pos^T, 1: S2=pred.pos^T).
// 512 threads = 8 waves; wave w owns rows w*32..w*32+31 (2 row-tiles of 16).
__global__ __launch_bounds__(512) void logits_mfma_kernel(
    const u16* __restrict__ f_bf,
    const u16* __restrict__ pred, const u16* __restrict__ pos,
    float* __restrict__ partial)
{
    __shared__ u16 lds[Nn * Dd];   // 64 KB swizzled pos[p] tile
    const int tid = threadIdx.x;
    const int p = blockIdx.x;
    const int sel = blockIdx.y;
    const int w = tid >> 6;
    const int l = tid & 63;
    const int r0 = w * 32;

    {
        const uint4* src = reinterpret_cast<const uint4*>(pos + (size_t)p * (Nn * Dd));
#pragma unroll
        for (int it = 0; it < 8; ++it) {
            int j = tid + 512 * it;
            int row = j >> 4;
            int colb = (j & 15) << 4;
            uint4 v = src[j];
            *reinterpret_cast<uint4*>((char*)lds + row * 256 + (colb ^ ((row & 7) << 4))) = v;
        }
    }

    const u16* Abase = sel ? (pred + (size_t)p * (Nn * Dd)) : f_bf;
    bf16x8 A[2][4];
    {
        const int arow = l & 15;
        const int acol = (l >> 4) << 4;
#pragma unroll
        for (int rt = 0; rt < 2; ++rt)
#pragma unroll
            for (int kk = 0; kk < 4; ++kk) {
                const char* ap = (const char*)Abase
                               + (size_t)(r0 + rt * 16 + arow) * 256 + kk * 64 + acol;
                A[rt][kk] = *reinterpret_cast<const bf16x8*>(ap);
            }
    }

    __syncthreads();

    const float L2E = 1.4426950408889634f;
    float s_[2][4];
    float dg[2][4];
#pragma unroll
    for (int rt = 0; rt < 2; ++rt)
#pragma unroll
        for (int r = 0; r < 4; ++r) { s_[rt][r] = 0.f; dg[rt][r] = 0.f; }

    const int mcol = l & 15;
    const int bcol = (l >> 4) << 4;

    for (int ct = 0; ct < 16; ++ct) {
        bf16x8 B[4];
        const int mrow = ct * 16 + mcol;
#pragma unroll
        for (int kk = 0; kk < 4; ++kk) {
            int cb = kk * 64 + bcol;
            B[kk] = *reinterpret_cast<const bf16x8*>(
                (const char*)lds + mrow * 256 + (cb ^ ((mrow & 7) << 4)));
        }
#pragma unroll
        for (int rt = 0; rt < 2; ++rt) {
            f32x4 acc = {0.f, 0.f, 0.f, 0.f};
#pragma unroll
            for (int kk = 0; kk < 4; ++kk)
                acc = __builtin_amdgcn_mfma_f32_16x16x32_bf16(A[rt][kk], B[kk], acc, 0, 0, 0);
            const bool isdg_ct = (ct == ((r0 >> 4) + rt));
#pragma unroll
            for (int r = 0; r < 4; ++r) {
                float v = acc[r];
                s_[rt][r] += __builtin_amdgcn_exp2f(fmaf(v, L2E, -64.f));
                if (isdg_ct && ((l & 15) == (((l >> 4) << 2) + r))) dg[rt][r] = v;
            }
        }
    }

    float local = 0.f;
#pragma unroll
    for (int rt = 0; rt < 2; ++rt)
#pragma unroll
        for (int r = 0; r < 4; ++r) {
            float s = s_[rt][r];
            s += __shfl_xor(s, 1);
            s += __shfl_xor(s, 2);
            s += __shfl_xor(s, 4);
            s += __shfl_xor(s, 8);
            if ((l & 15) == (((l >> 4) << 2) + r))
                local += 0.6931471805599453f * (64.f + __log2f(s)) - dg[rt][r];
        }

    __syncthreads();
    float* red = reinterpret_cast<float*>(lds);
    red[tid] = local;
    __syncthreads();
    for (int k = 256; k > 0; k >>= 1) {
        if (tid < k) red[tid] += red[tid + k];
        __syncthreads();
    }
    if (tid == 0) partial[p * 2 + sel] = red[0];
}

// ---------------- K4: deterministic final reduce ----------------
__global__ __launch_bounds__(256) void reduce_kernel(
    const float* __restrict__ partial, float* __restrict__ out)
{
    __shared__ float red[256];
    float s = 0.f;
    for (int i = threadIdx.x; i < 2 * Pp; i += 256) s += partial[i];
    red[threadIdx.x] = s;
    __syncthreads();
    for (int k = 128; k > 0; k >>= 1) {
        if (threadIdx.x < k) red[threadIdx.x] += red[threadIdx.x + k];
        __syncthreads();
    }
    if (threadIdx.x == 0) out[0] = red[0] * (1.0f / (Pp * (float)Nn));
}

extern "C" void kernel_launch(void* const* d_in, const int* in_sizes, int n_in,
                              void* d_out, int out_size, void* d_ws, size_t ws_size,
                              hipStream_t stream)
{
    const float* f   = (const float*)d_in[0];
    const float* x_t = (const float*)d_in[1];
    const float* x_p = (const float*)d_in[2];
    const float* m_t = (const float*)d_in[3];
    const float* m_p = (const float*)d_in[4];
    const float* c_t = (const float*)d_in[5];
    const float* c_p = (const float*)d_in[6];
    const float* W   = (const float*)d_in[7];
    const float* b   = (const float*)d_in[8];

    char* ws = (char*)d_ws;
    const size_t SLAB = (size_t)Pp * Nn * Dd;     // 9,011,200 elems

    float* bias_t = (float*)ws;                          // 131072 B
    float* bias_p = bias_t + Nn * Dd;                    // 131072 B
    u16* f_bf = (u16*)(ws + 262144);                     // 65536 B
    u16* WlT  = f_bf + Nn * Dd;                          // 32768 B
    u16* pred = (u16*)(ws + 360448);
    u16* pos  = pred + SLAB;
    float* partial = (float*)(pos + SLAB);

    bias_kernel<<<dim3(Nn * Dd / 256), 256, 0, stream>>>(m_t, m_p, c_t, c_p, W, b, f,
                                                         bias_t, bias_p, f_bf, WlT);
    join_direct_kernel<<<dim3(5, Nn), 256, 0, stream>>>(x_t, x_p, WlT, bias_t, bias_p,
                                                        pred, pos);
    logits_mfma_kernel<<<dim3(Pp, 2), 512, 0, stream>>>(f_bf, pred, pos, partial);
    reduce_kernel<<<1, 256, 0, stream>>>(partial, (float*)d_out);
}